// Round 18
// baseline (1048.213 us; speedup 1.0000x reference)
//
#include <hip/hip_runtime.h>
#include <stdint.h>

#define CDIV(a,b) (((a)+(b)-1)/(b))

typedef __attribute__((ext_vector_type(4))) float f32x4;
typedef __attribute__((ext_vector_type(8))) short s16x8;
typedef __attribute__((ext_vector_type(8))) unsigned short u16x8;
typedef __attribute__((ext_vector_type(4))) unsigned short u16x4;

__device__ __forceinline__ float bf2f(unsigned short u) {
  union { unsigned int i; float f; } c; c.i = ((unsigned int)u) << 16; return c.f;
}
__device__ __forceinline__ unsigned short f2bf(float f) {
  union { float f; unsigned int i; } c; c.f = f;
  unsigned int u = c.i;
  u += 0x7fffu + ((u >> 16) & 1u);
  return (unsigned short)(u >> 16);
}

#define KVROWS 80  // kvT rows per (b,h): 0-63 kv, 64 kfsum(bf16), 65-79 garbage (cols discarded)

// ===== QKV GEMM: kvqh[z][r][c] = (xbf @ W^T), 1D XCD-local grid =====
__global__ __launch_bounds__(256) void gemm_qkv(
    const unsigned short* __restrict__ A, const unsigned short* __restrict__ B,
    unsigned short* __restrict__ Cout, int Mb, long zsC, int Mstore)
{
  constexpr int LDT = 40;
  __shared__ unsigned short As[128 * LDT];
  __shared__ unsigned short Bs[128 * LDT];
  const int tid = threadIdx.x, wid = tid >> 6, lane = tid & 63;
  const int l15 = lane & 15, hi = lane >> 4;
  const int wr = wid >> 1, wc = wid & 1;
  const int idx = blockIdx.x;
  const int rest = idx >> 3;
  const int cblk = rest % 12;
  const int panel = (rest / 12) * 8 + (idx & 7);
  if (panel >= Mb) return;
  long m0 = (long)panel * 128;
  const int n0 = cblk * 128;
  f32x4 acc[4][4] = {};
  for (int k0 = 0; k0 < 512; k0 += 32) {
    #pragma unroll
    for (int c = tid; c < 512; c += 256) {
      int row = c >> 2, c8 = (c & 3) * 8;
      *(u16x8*)(&As[row * LDT + c8]) = *(const u16x8*)(A + (m0 + row) * 512 + k0 + c8);
      *(u16x8*)(&Bs[row * LDT + c8]) = *(const u16x8*)(B + (long)(n0 + row) * 512 + k0 + c8);
    }
    __syncthreads();
    s16x8 af[4], bfv[4];
    #pragma unroll
    for (int mt = 0; mt < 4; mt++)
      af[mt] = *(const s16x8*)(&As[(wr * 64 + mt * 16 + l15) * LDT + hi * 8]);
    #pragma unroll
    for (int nt = 0; nt < 4; nt++)
      bfv[nt] = *(const s16x8*)(&Bs[(wc * 64 + nt * 16 + l15) * LDT + hi * 8]);
    #pragma unroll
    for (int mt = 0; mt < 4; mt++)
      #pragma unroll
      for (int nt = 0; nt < 4; nt++)
        acc[mt][nt] = __builtin_amdgcn_mfma_f32_16x16x32_bf16(bfv[nt], af[mt], acc[mt][nt], 0, 0, 0);
    __syncthreads();
  }
  #pragma unroll
  for (int mt = 0; mt < 4; mt++) {
    long r = m0 + wr * 64 + mt * 16 + l15;
    if (r < Mstore) {
      #pragma unroll
      for (int nt = 0; nt < 4; nt++) {
        const int col0 = n0 + wc * 64 + nt * 16 + hi * 4;
        u16x4 o;
        #pragma unroll
        for (int i = 0; i < 4; i++) o[i] = f2bf(acc[mt][nt][i]);
        *(u16x4*)(Cout + (long)(col0 >> 6) * zsC + r * 64 + (col0 & 63)) = o;
      }
    }
  }
}

// ===== GEMM: C[M,N] = A(bf16)[M,K] * B(bf16)[N,K]^T (Wo path) =====
template<int BM, int BN, int WM, int WN, int EPI, int GSWAP>
__global__ __launch_bounds__(256) void gemm_bt(
    const unsigned short* __restrict__ A, const unsigned short* __restrict__ B,
    void* __restrict__ Cout, const float* __restrict__ aux,
    int K, int lda, int ldb, int ldc, long zsC, int Mstore)
{
  constexpr int MT = BM / (WM * 16);
  constexpr int NT = BN / (WN * 16);
  constexpr int LDT = 40;
  __shared__ unsigned short As[BM * LDT];
  __shared__ unsigned short Bs[BN * LDT];
  const int tid = threadIdx.x, wid = tid >> 6, lane = tid & 63;
  const int l15 = lane & 15, hi = lane >> 4;
  const int wr = wid / WN, wc = wid % WN;
  const int bx = GSWAP ? blockIdx.y : blockIdx.x;
  const int by = GSWAP ? blockIdx.x : blockIdx.y;
  long m0 = (long)by * BM;
  const int n0 = bx * BN;
  f32x4 acc[MT][NT] = {};
  for (int k0 = 0; k0 < K; k0 += 32) {
    #pragma unroll
    for (int c = tid; c < BM * 4; c += 256) {
      int row = c >> 2, c8 = (c & 3) * 8;
      *(u16x8*)(&As[row * LDT + c8]) = *(const u16x8*)(A + (m0 + row) * lda + k0 + c8);
    }
    #pragma unroll
    for (int c = tid; c < BN * 4; c += 256) {
      int row = c >> 2, c8 = (c & 3) * 8;
      *(u16x8*)(&Bs[row * LDT + c8]) = *(const u16x8*)(B + (long)(n0 + row) * ldb + k0 + c8);
    }
    __syncthreads();
    s16x8 af[MT], bfv[NT];
    #pragma unroll
    for (int mt = 0; mt < MT; mt++)
      af[mt] = *(const s16x8*)(&As[(wr * MT * 16 + mt * 16 + l15) * LDT + hi * 8]);
    #pragma unroll
    for (int nt = 0; nt < NT; nt++)
      bfv[nt] = *(const s16x8*)(&Bs[(wc * NT * 16 + nt * 16 + l15) * LDT + hi * 8]);
    #pragma unroll
    for (int mt = 0; mt < MT; mt++)
      #pragma unroll
      for (int nt = 0; nt < NT; nt++)
        acc[mt][nt] = __builtin_amdgcn_mfma_f32_16x16x32_bf16(bfv[nt], af[mt], acc[mt][nt], 0, 0, 0);
    __syncthreads();
  }
  #pragma unroll
  for (int mt = 0; mt < MT; mt++) {
    long r = m0 + wr * (MT * 16) + mt * 16 + l15;
    if (r < Mstore) {
      #pragma unroll
      for (int nt = 0; nt < NT; nt++) {
        const int col0 = n0 + wc * (NT * 16) + nt * 16 + hi * 4;
        f32x4 v = acc[mt][nt];
        if constexpr (EPI == 8) {
          const f32x4 ax = *(const f32x4*)(aux + r * ldc + col0);
          f32x4 o;
          #pragma unroll
          for (int i = 0; i < 4; i++) o[i] = v[i] + ax[i];
          *(f32x4*)((float*)Cout + r * ldc + col0) = o;
        }
      }
    }
  }
}

// ===== conv GEMM with fused BN2 stats =====
__global__ __launch_bounds__(256) void gemm_conv_bn(
    const unsigned short* __restrict__ A, const unsigned short* __restrict__ B,
    float* __restrict__ out, const float* __restrict__ bias,
    float* __restrict__ s1, float* __restrict__ s2, int Mstore)
{
  constexpr int LDT = 40;
  __shared__ unsigned short As[128 * LDT];
  __shared__ unsigned short Bs[128 * LDT];
  const int tid = threadIdx.x, wid = tid >> 6, lane = tid & 63;
  const int l15 = lane & 15, hi = lane >> 4;
  const int wr = wid >> 1, wc = wid & 1;
  long m0 = (long)blockIdx.y * 128;
  const int n0 = blockIdx.x * 128;
  f32x4 acc[4][4] = {};
  for (int k0 = 0; k0 < 512; k0 += 32) {
    #pragma unroll
    for (int c = tid; c < 512; c += 256) {
      int row = c >> 2, c8 = (c & 3) * 8;
      *(u16x8*)(&As[row * LDT + c8]) = *(const u16x8*)(A + (m0 + row) * 512 + k0 + c8);
      *(u16x8*)(&Bs[row * LDT + c8]) = *(const u16x8*)(B + (long)(n0 + row) * 512 + k0 + c8);
    }
    __syncthreads();
    s16x8 af[4], bfv[4];
    #pragma unroll
    for (int mt = 0; mt < 4; mt++)
      af[mt] = *(const s16x8*)(&As[(wr * 64 + mt * 16 + l15) * LDT + hi * 8]);
    #pragma unroll
    for (int nt = 0; nt < 4; nt++)
      bfv[nt] = *(const s16x8*)(&Bs[(wc * 64 + nt * 16 + l15) * LDT + hi * 8]);
    #pragma unroll
    for (int mt = 0; mt < 4; mt++)
      #pragma unroll
      for (int nt = 0; nt < 4; nt++)
        acc[mt][nt] = __builtin_amdgcn_mfma_f32_16x16x32_bf16(bfv[nt], af[mt], acc[mt][nt], 0, 0, 0);
    __syncthreads();
  }
  float st[4][4] = {};
  float sq[4][4] = {};
  #pragma unroll
  for (int mt = 0; mt < 4; mt++) {
    long r = m0 + wr * 64 + mt * 16 + l15;
    bool valid = r < Mstore;
    #pragma unroll
    for (int nt = 0; nt < 4; nt++) {
      const int col0 = n0 + wc * 64 + nt * 16 + hi * 4;
      f32x4 o = {0.f, 0.f, 0.f, 0.f};
      if (valid) {
        float* cp = out + r * 512 + col0;
        f32x4 cur = *(f32x4*)cp;
        #pragma unroll
        for (int i = 0; i < 4; i++) {
          float cv = acc[mt][nt][i] + bias[col0 + i];
          cv = cv > 0.f ? cv : 0.f;
          o[i] = cur[i] + cv;
        }
        *(f32x4*)cp = o;
      }
      #pragma unroll
      for (int i = 0; i < 4; i++) { st[nt][i] += o[i]; sq[nt][i] += o[i] * o[i]; }
    }
  }
  #pragma unroll
  for (int nt = 0; nt < 4; nt++)
    #pragma unroll
    for (int i = 0; i < 4; i++) {
      float a = st[nt][i], b = sq[nt][i];
      a += __shfl_xor(a, 1); a += __shfl_xor(a, 2); a += __shfl_xor(a, 4); a += __shfl_xor(a, 8);
      b += __shfl_xor(b, 1); b += __shfl_xor(b, 2); b += __shfl_xor(b, 4); b += __shfl_xor(b, 8);
      if (l15 == 0) {
        const int col = n0 + wc * 64 + nt * 16 + hi * 4 + i;
        atomicAdd(&s1[col], a);
        atomicAdd(&s2[col], b);
      }
    }
}

// ===== k-side pass 1: per-graph-per-head max of u (no stores); 1D grid, bh=idx&255 =====
__global__ __launch_bounds__(256, 4) void k_kmax(
    const unsigned short* __restrict__ kvqh, const unsigned short* __restrict__ projb,
    const unsigned int* __restrict__ offs, unsigned int* __restrict__ kmax, long Npad) {
  __shared__ float wmax[4];
  const int tid = threadIdx.x, wid = tid >> 6, lane = tid & 63;
  const int bh = blockIdx.x & 255, xb = blockIdx.x >> 8;
  const int b = bh >> 3, h = bh & 7;
  const unsigned int off = offs[b];
  const int nb = (int)(offs[b + 1] - off);
  const int m0 = xb * 64;
  if (m0 >= nb) return;
  const unsigned short* A = kvqh + ((long)(8 + h) * Npad + off + m0) * 64;
  f32x4 acc[4][4] = {};
  #pragma unroll
  for (int k0 = 0; k0 < 64; k0 += 32) {
    s16x8 af[4], bfv[4];
    #pragma unroll
    for (int mt = 0; mt < 4; mt++)
      af[mt] = *(const s16x8*)(A + (long)(mt * 16 + (lane & 15)) * 64 + k0 + ((lane >> 4) * 8));
    #pragma unroll
    for (int nt = 0; nt < 4; nt++)
      bfv[nt] = *(const s16x8*)(projb + (long)(wid * 64 + nt * 16 + (lane & 15)) * 64 + k0 + ((lane >> 4) * 8));
    __builtin_amdgcn_s_setprio(1);
    #pragma unroll
    for (int mt = 0; mt < 4; mt++)
      #pragma unroll
      for (int nt = 0; nt < 4; nt++)
        acc[mt][nt] = __builtin_amdgcn_mfma_f32_16x16x32_bf16(af[mt], bfv[nt], acc[mt][nt], 0, 0, 0);
    __builtin_amdgcn_s_setprio(0);
  }
  float bm = -3.0e38f;
  #pragma unroll
  for (int mt = 0; mt < 4; mt++)
    #pragma unroll
    for (int i = 0; i < 4; i++) {
      int row = mt * 16 + ((lane >> 4) << 2) + i;
      if (m0 + row < nb) {
        #pragma unroll
        for (int nt = 0; nt < 4; nt++) bm = fmaxf(bm, acc[mt][nt][i]);
      }
    }
  #pragma unroll
  for (int s = 1; s < 64; s <<= 1) bm = fmaxf(bm, __shfl_xor(bm, s));
  if (lane == 0) wmax[wid] = bm;
  __syncthreads();
  if (tid == 0) {
    float m = fmaxf(fmaxf(wmax[0], wmax[1]), fmaxf(wmax[2], wmax[3]));
    atomicMax(&kmax[b * 8 + h], __float_as_uint(fmaxf(m, 0.f)));
  }
}

// ===== k-side pass 2: m-split kv accumulation; kfsum -> bf16 row 64; 1D grid =====
__global__ __launch_bounds__(256) void k_kvm(
    const unsigned short* __restrict__ kvqh, const unsigned short* __restrict__ projb,
    const unsigned int* __restrict__ offs, const unsigned int* __restrict__ kmax,
    unsigned short* __restrict__ kvTb, long Npad) {
  constexpr int TLD = 72;
  __shared__ unsigned short vsT[2][64 * TLD];
  __shared__ unsigned short kfsT[64 * TLD];
  const int tid = threadIdx.x, wid = tid >> 6, lane = tid & 63;
  const int bh = blockIdx.x & 255, mblk = blockIdx.x >> 8;
  const int b = bh >> 3, h = bh & 7;
  const unsigned int off = offs[b];
  const int nb = (int)(offs[b + 1] - off);
  const float km = __uint_as_float(kmax[b * 8 + h]);
  const unsigned short* Kp = kvqh + ((long)(8 + h) * Npad + off) * 64;
  const unsigned short* Vp = kvqh + ((long)(16 + h) * Npad + off) * 64;
  const unsigned short* Pp = projb + (long)(mblk * 64 + wid * 16) * 64;
  const int l15 = lane & 15, hi = lane >> 4;
  const int mloc = wid * 16 + l15;

  #pragma unroll
  for (int c = tid; c < 512; c += 256) {
    int row = c >> 3, c8 = (c & 7) * 8;
    int rot = (c & 7) * 8;
    u16x8 v = *(const u16x8*)(Vp + (long)row * 64 + c8);
    #pragma unroll
    for (int j = 0; j < 8; j++) vsT[0][(c8 + j) * TLD + ((row + rot) & 63)] = v[j];
  }
  __syncthreads();

  f32x4 akv[4] = {};
  float ksum = 0.f;
  int buf = 0;
  for (int n0 = 0; n0 < nb; n0 += 64) {
    f32x4 acc[4] = {};
    float dsum[4] = {0.f, 0.f, 0.f, 0.f};
    #pragma unroll
    for (int k0 = 0; k0 < 64; k0 += 32) {
      s16x8 af[4];
      #pragma unroll
      for (int mt = 0; mt < 4; mt++)
        af[mt] = *(const s16x8*)(Kp + ((long)n0 + mt * 16 + l15) * 64 + k0 + hi * 8);
      s16x8 bfv = *(const s16x8*)(Pp + (long)l15 * 64 + k0 + hi * 8);
      __builtin_amdgcn_s_setprio(1);
      #pragma unroll
      for (int mt = 0; mt < 4; mt++) {
        #pragma unroll
        for (int j = 0; j < 8; j++) {
          float a = bf2f((unsigned short)af[mt][j]);
          dsum[mt] += a * a;
        }
        acc[mt] = __builtin_amdgcn_mfma_f32_16x16x32_bf16(af[mt], bfv, acc[mt], 0, 0, 0);
      }
      __builtin_amdgcn_s_setprio(0);
    }
    float rs[4];
    #pragma unroll
    for (int mt = 0; mt < 4; mt++) {
      float s = dsum[mt];
      s += __shfl_xor(s, 16); s += __shfl_xor(s, 32);
      rs[mt] = 0.0625f * s;
    }
    #pragma unroll
    for (int mt = 0; mt < 4; mt++) {
      int r0 = mt * 16 + hi * 4;
      float e[4];
      #pragma unroll
      for (int i = 0; i < 4; i++) {
        float dg = __shfl(rs[mt], hi * 4 + i);
        e[i] = (n0 + r0 + i < nb) ? (__expf(acc[mt][i] - dg - km) * 0.0625f + 1e-6f) : 0.f;
      }
      ksum += e[0] + e[1] + e[2] + e[3];
      unsigned int p0 = (unsigned int)f2bf(e[0]) | ((unsigned int)f2bf(e[1]) << 16);
      unsigned int p1 = (unsigned int)f2bf(e[2]) | ((unsigned int)f2bf(e[3]) << 16);
      *(unsigned int*)(&kfsT[mloc * TLD + r0]) = p0;
      *(unsigned int*)(&kfsT[mloc * TLD + r0 + 2]) = p1;
    }
    if (n0 + 64 < nb) {
      #pragma unroll
      for (int c = tid; c < 512; c += 256) {
        int row = c >> 3, c8 = (c & 7) * 8;
        int rot = (c & 7) * 8;
        u16x8 v = *(const u16x8*)(Vp + ((long)n0 + 64 + row) * 64 + c8);
        #pragma unroll
        for (int j = 0; j < 8; j++) vsT[buf ^ 1][(c8 + j) * TLD + ((row + rot) & 63)] = v[j];
      }
    }
    __builtin_amdgcn_s_setprio(1);
    #pragma unroll
    for (int ks = 0; ks < 2; ks++) {
      s16x8 bB = *(const s16x8*)(&kfsT[mloc * TLD + ks * 32 + hi * 8]);
      #pragma unroll
      for (int mt2 = 0; mt2 < 4; mt2++) {
        int d = mt2 * 16 + l15;
        int rrot = ((ks * 32 + hi * 8) + ((d >> 3) & 7) * 8) & 63;
        s16x8 aA = *(const s16x8*)(&vsT[buf][d * TLD + rrot]);
        akv[mt2] = __builtin_amdgcn_mfma_f32_16x16x32_bf16(aA, bB, akv[mt2], 0, 0, 0);
      }
    }
    __builtin_amdgcn_s_setprio(0);
    __syncthreads();
    buf ^= 1;
  }
  long base = ((long)b * 8 + h) * (KVROWS * 256);
  const int m = mblk * 64 + mloc;
  #pragma unroll
  for (int mt2 = 0; mt2 < 4; mt2++)
    #pragma unroll
    for (int i = 0; i < 4; i++) {
      int d = mt2 * 16 + hi * 4 + i;
      kvTb[base + (long)d * 256 + m] = f2bf(akv[mt2][i]);
    }
  ksum += __shfl_xor(ksum, 16); ksum += __shfl_xor(ksum, 32);
  if (hi == 0) kvTb[base + 64 * 256 + m] = f2bf(ksum);
}

// ===== query-side flash: 32-row tile (LDS 17.4KB -> ~8 blocks/CU), bounds(256,4)
// so the allocator has headroom (r16 lesson: (256,8) forced 32 VGPR -> spills).
// Swapped layout, packed stores, fused denominator; waves 2-3 exit before PV;
// 1D XCD-local grid (bh = idx&255). =====
__global__ __launch_bounds__(256, 4) void k_qflash(
    const unsigned short* __restrict__ qh_all, const unsigned short* __restrict__ projb,
    const unsigned short* __restrict__ kvTb, const unsigned int* __restrict__ offs,
    unsigned short* __restrict__ attn, long Npad) {
  constexpr int QLDT = 264;
  __shared__ unsigned short qfs[32 * QLDT];
  __shared__ float smax[4][32];
  const int tid = threadIdx.x, wid = tid >> 6, lane = tid & 63;
  const int l15 = lane & 15, hi = lane >> 4;
  const int bh = blockIdx.x & 255, xb = blockIdx.x >> 8;
  const int b = bh >> 3, h = bh & 7;
  const unsigned int off = offs[b];
  const int nb = (int)(offs[b + 1] - off);
  const int m0 = xb * 32;
  if (m0 >= nb) return;
  const unsigned short* A = qh_all + ((long)h * Npad + off + m0) * 64;

  // --- u-phase: rows = mt*16+l15 (mt<2), cols = wid*64 + nt*16 + hi*4 ---
  f32x4 acc[2][4] = {};
  float dsum[2] = {0.f, 0.f};
  #pragma unroll
  for (int k0 = 0; k0 < 64; k0 += 32) {
    s16x8 af[2], bfv[4];
    #pragma unroll
    for (int mt = 0; mt < 2; mt++)
      af[mt] = *(const s16x8*)(A + (long)(mt * 16 + l15) * 64 + k0 + hi * 8);
    #pragma unroll
    for (int nt = 0; nt < 4; nt++)
      bfv[nt] = *(const s16x8*)(projb + (long)(wid * 64 + nt * 16 + l15) * 64 + k0 + hi * 8);
    #pragma unroll
    for (int mt = 0; mt < 2; mt++)
      #pragma unroll
      for (int j = 0; j < 8; j++) {
        float a = bf2f((unsigned short)af[mt][j]);
        dsum[mt] += a * a;
      }
    __builtin_amdgcn_s_setprio(1);
    #pragma unroll
    for (int mt = 0; mt < 2; mt++)
      #pragma unroll
      for (int nt = 0; nt < 4; nt++)
        acc[mt][nt] = __builtin_amdgcn_mfma_f32_16x16x32_bf16(bfv[nt], af[mt], acc[mt][nt], 0, 0, 0);
    __builtin_amdgcn_s_setprio(0);
  }
  float diag[2];
  #pragma unroll
  for (int mt = 0; mt < 2; mt++) {
    float s = dsum[mt];
    s += __shfl_xor(s, 16); s += __shfl_xor(s, 32);
    diag[mt] = 0.0625f * s;
  }
  #pragma unroll
  for (int mt = 0; mt < 2; mt++) {
    float m = acc[mt][0][0];
    #pragma unroll
    for (int nt = 0; nt < 4; nt++)
      #pragma unroll
      for (int i = 0; i < 4; i++) m = fmaxf(m, acc[mt][nt][i]);
    m = fmaxf(m, __shfl_xor(m, 16)); m = fmaxf(m, __shfl_xor(m, 32));
    if (hi == 0) smax[wid][mt * 16 + l15] = m;
  }
  __syncthreads();
  #pragma unroll
  for (int mt = 0; mt < 2; mt++) {
    int row = mt * 16 + l15;
    float rm = fmaxf(fmaxf(smax[0][row], smax[1][row]), fmaxf(smax[2][row], smax[3][row]));
    float sub = diag[mt] + rm;
    #pragma unroll
    for (int nt = 0; nt < 4; nt++) {
      u16x4 o;
      #pragma unroll
      for (int i = 0; i < 4; i++)
        o[i] = f2bf(__expf(acc[mt][nt][i] - sub) * 0.0625f + 1e-6f);
      *(u16x4*)(&qfs[row * QLDT + wid * 64 + nt * 16 + hi * 4]) = o;
    }
  }
  __syncthreads();
  if (wid >= 2) return;  // waves 2-3 done; PV handled by waves 0-1 (16 rows each)
  const unsigned short* kvb = kvTb + ((long)b * 8 + h) * (KVROWS * 256);
  f32x4 acc2[4] = {};
  f32x4 acc3 = {};
  s16x8 bkc[5];
  #pragma unroll
  for (int t = 0; t < 5; t++)
    bkc[t] = *(const s16x8*)(kvb + (long)(t * 16 + l15) * 256 + hi * 8);
  #pragma unroll
  for (int ks = 0; ks < 8; ks++) {
    s16x8 bkn[5];
    if (ks < 7) {
      #pragma unroll
      for (int t = 0; t < 5; t++)
        bkn[t] = *(const s16x8*)(kvb + (long)(t * 16 + l15) * 256 + (ks + 1) * 32 + hi * 8);
    }
    s16x8 aq = *(const s16x8*)(&qfs[(wid * 16 + l15) * QLDT + ks * 32 + hi * 8]);
    __builtin_amdgcn_s_setprio(1);
    #pragma unroll
    for (int t = 0; t < 4; t++)
      acc2[t] = __builtin_amdgcn_mfma_f32_16x16x32_bf16(bkc[t], aq, acc2[t], 0, 0, 0);
    acc3 = __builtin_amdgcn_mfma_f32_16x16x32_bf16(bkc[4], aq, acc3, 0, 0, 0);
    __builtin_amdgcn_s_setprio(0);
    if (ks < 7) {
      #pragma unroll
      for (int t = 0; t < 5; t++) bkc[t] = bkn[t];
    }
  }
  float zden = __shfl(acc3[0], l15);
  float zr = 1.f / (zden + 1e-6f);
  int row = wid * 16 + l15;
  if (m0 + row < nb) {
    unsigned short* po = attn + (long)(off + m0 + row) * 512 + h * 64;
    #pragma unroll
    for (int t = 0; t < 4; t++) {
      u16x4 o;
      #pragma unroll
      for (int i = 0; i < 4; i++) o[i] = f2bf(acc2[t][i] * zr);
      *(u16x4*)(po + t * 16 + hi * 4) = o;
    }
  }
}

// ===== small kernels =====

__global__ void k_fill(float* __restrict__ out, long n, float v) {
  long i = (long)blockIdx.x * 256 + threadIdx.x;
  if (i < n) out[i] = v;
}

__global__ void k_convx_stats(const float* __restrict__ x, unsigned short* __restrict__ xb,
                              float* __restrict__ s1, float* __restrict__ s2, int N, int rpb) {
  int t = threadIdx.x;
  int r0 = blockIdx.x * rpb;
  int r1 = min(N, r0 + rpb);
  float a1 = 0, a2 = 0, b1 = 0, b2 = 0;
  for (int r = r0; r < r1; r++) {
    const float* xr = x + (long)r * 512 + 2 * t;
    float va = xr[0], vb = xr[1];
    a1 += va; a2 += va * va; b1 += vb; b2 += vb * vb;
    *(unsigned int*)(xb + (long)r * 512 + 2 * t) =
        (unsigned int)f2bf(va) | ((unsigned int)f2bf(vb) << 16);
  }
  atomicAdd(&s1[2 * t], a1); atomicAdd(&s2[2 * t], a2);
  atomicAdd(&s1[2 * t + 1], b1); atomicAdd(&s2[2 * t + 1], b2);
}

__global__ void k_transall(const float* __restrict__ w0, const float* __restrict__ w1,
                           const float* __restrict__ w2, const float* __restrict__ w3,
                           const float* __restrict__ w4, unsigned short* __restrict__ out) {
  long idx = (long)blockIdx.x * 256 + threadIdx.x;
  if (idx >= (5L << 18)) return;
  int which = (int)(idx >> 18);
  int r = (int)(idx & 262143);
  int n = r >> 9, k = r & 511;
  const float* w = which == 0 ? w0 : which == 1 ? w1 : which == 2 ? w2 : which == 3 ? w3 : w4;
  out[idx] = f2bf(w[k * 512 + n]);
}

__global__ void k_scale_copy_bf(const float* __restrict__ in, unsigned short* __restrict__ out,
                                int n, float scl) {
  int i = blockIdx.x * 256 + threadIdx.x;
  if (i < n) out[i] = f2bf(in[i] * scl);
}

__global__ void k_bn_final(const float* __restrict__ s1, const float* __restrict__ s2,
                           const float* __restrict__ g, const float* __restrict__ b,
                           float* __restrict__ a, float* __restrict__ c, float invN) {
  int t = threadIdx.x;
  float mu = s1[t] * invN;
  float var = s2[t] * invN - mu * mu;
  float inv = rsqrtf(var + 1e-5f);
  float av = g[t] * inv;
  a[t] = av;
  c[t] = b[t] - mu * av;
}

__global__ void k_deg(const int* __restrict__ ed, unsigned int* __restrict__ deg, long E) {
  long i = (long)blockIdx.x * 256 + threadIdx.x;
  if (i < E) atomicAdd(&deg[ed[i]], 1u);
}

__global__ void k_offs(const int* __restrict__ batch, unsigned int* __restrict__ offs, int N) {
  int i = blockIdx.x * 256 + threadIdx.x;
  if (i >= N) return;
  int b = batch[i];
  if (i == 0) { for (int bb = 0; bb <= b; bb++) offs[bb] = 0; }
  else {
    int pb = batch[i - 1];
    if (pb != b) for (int bb = pb + 1; bb <= b; bb++) offs[bb] = i;
  }
  if (i == N - 1) { for (int bb = b + 1; bb <= 32; bb++) offs[bb] = N; }
}

__global__ __launch_bounds__(1024) void k_scan_nodes(const unsigned int* __restrict__ deg,
                                                     unsigned int* __restrict__ rowstart, int N) {
  __shared__ unsigned int wsum[16];
  __shared__ unsigned int carry_s;
  int t = threadIdx.x, lane = t & 63, wid = t >> 6;
  if (t == 0) carry_s = 0;
  __syncthreads();
  for (int base = 0; base < N; base += 1024) {
    int i = base + t;
    unsigned int v = (i < N) ? deg[i] : 0;
    unsigned int sc = v;
    #pragma unroll
    for (int s = 1; s < 64; s <<= 1) {
      unsigned int u = __shfl_up(sc, s);
      if (lane >= s) sc += u;
    }
    if (lane == 63) wsum[wid] = sc;
    __syncthreads();
    unsigned int woff = 0, tot = 0;
    #pragma unroll
    for (int w = 0; w < 16; w++) { unsigned int s = wsum[w]; if (w < wid) woff += s; tot += s; }
    unsigned int carry = carry_s;
    if (i < N) rowstart[i] = carry + woff + sc - v;
    __syncthreads();
    if (t == 0) carry_s = carry + tot;
    __syncthreads();
  }
  if (threadIdx.x == 0) rowstart[N] = carry_s;
}

__global__ void k_csr_fill(const int* __restrict__ es, const int* __restrict__ ed,
                           const unsigned int* __restrict__ rowstart,
                           unsigned int* __restrict__ cursor, int* __restrict__ csr, long E) {
  long e = (long)blockIdx.x * 256 + threadIdx.x;
  if (e >= E) return;
  int d = ed[e];
  unsigned int slot = atomicAdd(&cursor[d], 1u);
  csr[rowstart[d] + slot] = es[e];
}

// gather from bf16 xbf; fused deg-normalize + BN1 affine
__global__ __launch_bounds__(128) void k_gather(const int* __restrict__ csr,
                                                const unsigned int* __restrict__ rowstart,
                                                const unsigned short* __restrict__ xb,
                                                const float* __restrict__ a1, const float* __restrict__ c1,
                                                unsigned short* __restrict__ conv_in, int N) {
  long n = blockIdx.x;
  int c = threadIdx.x * 4;
  u16x4 o; o[0] = 0; o[1] = 0; o[2] = 0; o[3] = 0;
  if (n < N) {
    unsigned int r0 = rowstart[n], r1 = rowstart[n + 1];
    if (r1 > r0) {
      f32x4 acc0 = {}, acc1 = {};
      unsigned int j = r0;
      for (; j + 2 <= r1; j += 2) {
        u16x4 v0 = *(const u16x4*)(xb + (long)csr[j] * 512 + c);
        u16x4 v1 = *(const u16x4*)(xb + (long)csr[j + 1] * 512 + c);
        #pragma unroll
        for (int i = 0; i < 4; i++) { acc0[i] += bf2f(v0[i]); acc1[i] += bf2f(v1[i]); }
      }
      if (j < r1) {
        u16x4 v0 = *(const u16x4*)(xb + (long)csr[j] * 512 + c);
        #pragma unroll
        for (int i = 0; i < 4; i++) acc0[i] += bf2f(v0[i]);
      }
      f32x4 acc = acc0 + acc1;
      float inv = 1.f / (float)(r1 - r0);
      o[0] = f2bf(acc[0] * inv * a1[c + 0] + c1[c + 0]);
      o[1] = f2bf(acc[1] * inv * a1[c + 1] + c1[c + 1]);
      o[2] = f2bf(acc[2] * inv * a1[c + 2] + c1[c + 2]);
      o[3] = f2bf(acc[3] * inv * a1[c + 3] + c1[c + 3]);
    }
  }
  *(u16x4*)(conv_in + n * 512 + c) = o;
}

__global__ void k_bn_apply(float* __restrict__ y, const float* __restrict__ a,
                           const float* __restrict__ c, long total) {
  long i4 = ((long)blockIdx.x * 256 + threadIdx.x) * 4;
  if (i4 >= total) return;
  int col = (int)(i4 & 511);
  f32x4 v = *(const f32x4*)(y + i4);
  #pragma unroll
  for (int j = 0; j < 4; j++) v[j] = v[j] * a[col + j] + c[col + j];
  *(f32x4*)(y + i4) = v;
}

// ===== host =====

extern "C" void kernel_launch(void* const* d_in, const int* in_sizes, int n_in,
                              void* d_out, int out_size, void* d_ws, size_t ws_size,
                              hipStream_t stream) {
  (void)n_in; (void)out_size;
  const float* x = (const float*)d_in[0];
  const int* batch = (const int*)d_in[1];
  const int* eidx = (const int*)d_in[2];
  const float* n1g = (const float*)d_in[3];
  const float* n1b = (const float*)d_in[4];
  const float* n2g = (const float*)d_in[5];
  const float* n2b = (const float*)d_in[6];
  const float* wconv = (const float*)d_in[7];
  const float* bconv = (const float*)d_in[8];
  const float* wq = (const float*)d_in[9];
  const float* wk = (const float*)d_in[10];
  const float* wv = (const float*)d_in[11];
  const float* wo = (const float*)d_in[12];
  const float* proj = (const float*)d_in[13];

  const int N = in_sizes[1];
  const long E = in_sizes[2] / 2;
  const long Npad = CDIV(N, 128) * 128 + 256;
  const int Mb = (int)((CDIV(N, 128) * 128 + 128) / 128);  // QKV panel count (padded)
  const int MbC = CDIV(N, 128);                            // exact panel count for out-path GEMMs
  const int* es = eidx;
  const int* ed = eidx + E;
  float* out = (float*)d_out;

  char* p = (char*)d_ws;
  auto alloc = [&](size_t bytes) -> char* {
    char* r = p;
    p += (bytes + 255) & ~(size_t)255;
    return r;
  };
  unsigned short* kvqh = (unsigned short*)alloc((size_t)24 * Npad * 64 * 2);  // q:0-7,k:8-15,v:16-23 (k+v -> attn)
  unsigned short* xbf  = (unsigned short*)alloc((size_t)Npad * 512 * 2);      // x bf16 (gather source)
  unsigned short* conv_in = (unsigned short*)alloc((size_t)Npad * 512 * 2);   // gather output
  unsigned short* kvT_b = (unsigned short*)alloc((size_t)32 * 8 * KVROWS * 256 * 2);
  unsigned short* wts   = (unsigned short*)alloc((size_t)5 * 512 * 512 * 2);  // q|k|v|conv|o transposed
  unsigned short* proj_s = (unsigned short*)alloc((size_t)256 * 64 * 2);
  float* bn1_acc = (float*)alloc(1024 * 4);
  float* bn1_ac  = (float*)alloc(1024 * 4);
  float* bn2_acc = (float*)alloc(1024 * 4);
  float* bn2_ac  = (float*)alloc(1024 * 4);
  unsigned int* deg      = (unsigned int*)alloc((size_t)N * 4);
  unsigned int* offs     = (unsigned int*)alloc(33 * 4);
  unsigned int* kmax     = (unsigned int*)alloc(32 * 8 * 4);
  unsigned int* rowstart = (unsigned int*)alloc((size_t)(N + 1) * 4);
  unsigned int* cursor   = (unsigned int*)alloc((size_t)N * 4);
  int* csr               = (int*)alloc((size_t)E * 4);
  size_t required = (size_t)(p - (char*)d_ws);
  if (required > ws_size) {
    k_fill<<<(int)CDIV((long)N * 512, 256), 256, 0, stream>>>(
        out, (long)N * 512, 1.0e6f + (float)(ws_size >> 20));
    return;
  }
  unsigned short* wqkv_t  = wts;
  unsigned short* wconv_t = wts + 3 * 512 * 512;
  unsigned short* wo_t    = wts + 4 * 512 * 512;
  unsigned short* attn2   = kvqh + (size_t)8 * Npad * 64;  // overlays k+v heads (dead after kvm)

  // ---- zero accumulators (ws is not re-poisoned between replays) ----
  hipMemsetAsync(deg, 0, (size_t)N * 4, stream);
  hipMemsetAsync(cursor, 0, (size_t)N * 4, stream);
  hipMemsetAsync(kmax, 0, 32 * 8 * 4, stream);
  hipMemsetAsync(bn1_acc, 0, 1024 * 4, stream);
  hipMemsetAsync(bn2_acc, 0, 1024 * 4, stream);
  hipMemsetAsync(xbf + (size_t)N * 512, 0, (size_t)(Npad - N) * 512 * 2, stream);

  // ---- prep ----
  int rpb = CDIV(N, 1024);
  k_convx_stats<<<1024, 256, 0, stream>>>(x, xbf, bn1_acc, bn1_acc + 512, N, rpb);
  k_transall<<<(int)CDIV(5L << 18, 256), 256, 0, stream>>>(wq, wk, wv, wconv, wo, wts);
  k_scale_copy_bf<<<CDIV(256 * 64, 256), 256, 0, stream>>>(proj, proj_s, 256 * 64, 0.35355339059327373f);
  k_bn_final<<<1, 512, 0, stream>>>(bn1_acc, bn1_acc + 512, n1g, n1b, bn1_ac, bn1_ac + 512, 1.f / N);
  k_deg<<<(int)CDIV(E, 256), 256, 0, stream>>>(ed, deg, E);
  k_offs<<<CDIV(N, 256), 256, 0, stream>>>(batch, offs, N);
  k_scan_nodes<<<1, 1024, 0, stream>>>(deg, rowstart, N);
  k_csr_fill<<<(int)CDIV(E, 256), 256, 0, stream>>>(es, ed, rowstart, cursor, csr, E);

  // ---- QKV: 1D XCD-local grid (panel's 12 col-blocks on same XCD, back-to-back) ----
  const int MbP8 = CDIV(Mb, 8) * 8;
  gemm_qkv<<<MbP8 * 12, 256, 0, stream>>>(
      xbf, wqkv_t, kvqh, Mb, (long)Npad * 64, (int)Npad);

  // ---- keys: max pass, then m-split kv accumulation (1D XCD-local grids) ----
  k_kmax<<<32 * 256, 256, 0, stream>>>(kvqh, proj_s, offs, kmax, Npad);
  k_kvm<<<4 * 256, 256, 0, stream>>>(kvqh, proj_s, offs, kmax, kvT_b, Npad);

  // ---- GNN conv gather (reads bf16 xbf, writes dedicated conv_in) ----
  k_gather<<<MbC * 128, 128, 0, stream>>>(csr, rowstart, xbf, bn1_ac, bn1_ac + 512, conv_in, N);

  // ---- queries: 32-row flash kernel, bounds(256,4); attn into dead k/v region ----
  k_qflash<<<64 * 256, 256, 0, stream>>>(
      kvqh, proj_s, kvT_b, offs, attn2, Npad);

  // ---- output projection + residual x (EPI8, col-fast grid order) ----
  gemm_bt<128, 128, 2, 2, 8, 0><<<dim3(4, MbC), 256, 0, stream>>>(
      attn2, wo_t, out, x, 512, 512, 512, 512, 0, N);

  // ---- conv GEMM + fused BN2 stats (last writer of out; col-fast grid order) ----
  gemm_conv_bn<<<dim3(4, MbC), 256, 0, stream>>>(
      conv_in, wconv_t, out, bconv, bn2_acc, bn2_acc + 512, N);

  // ---- BN2 finalize + apply ----
  k_bn_final<<<1, 512, 0, stream>>>(bn2_acc, bn2_acc + 512, n2g, n2b, bn2_ac, bn2_ac + 512, 1.f / N);
  k_bn_apply<<<(int)CDIV((long)N * 512 / 4, 256), 256, 0, stream>>>(out, bn2_ac, bn2_ac + 512, (long)N * 512);
}

// Round 19
// 1025.631 us; speedup vs baseline: 1.0220x; 1.0220x over previous
//
#include <hip/hip_runtime.h>
#include <stdint.h>

#define CDIV(a,b) (((a)+(b)-1)/(b))

typedef __attribute__((ext_vector_type(4))) float f32x4;
typedef __attribute__((ext_vector_type(8))) short s16x8;
typedef __attribute__((ext_vector_type(8))) unsigned short u16x8;
typedef __attribute__((ext_vector_type(4))) unsigned short u16x4;

__device__ __forceinline__ float bf2f(unsigned short u) {
  union { unsigned int i; float f; } c; c.i = ((unsigned int)u) << 16; return c.f;
}
__device__ __forceinline__ unsigned short f2bf(float f) {
  union { float f; unsigned int i; } c; c.f = f;
  unsigned int u = c.i;
  u += 0x7fffu + ((u >> 16) & 1u);
  return (unsigned short)(u >> 16);
}

#define KVROWS 80  // kvT rows per (b,h): 0-63 kv, 64 kfsum(bf16), 65-79 garbage (cols discarded)

// ===== QKV GEMM: kvqh[z][r][c] = (xbf @ W^T), 1D XCD-local grid =====
__global__ __launch_bounds__(256) void gemm_qkv(
    const unsigned short* __restrict__ A, const unsigned short* __restrict__ B,
    unsigned short* __restrict__ Cout, int Mb, long zsC, int Mstore)
{
  constexpr int LDT = 40;
  __shared__ unsigned short As[128 * LDT];
  __shared__ unsigned short Bs[128 * LDT];
  const int tid = threadIdx.x, wid = tid >> 6, lane = tid & 63;
  const int l15 = lane & 15, hi = lane >> 4;
  const int wr = wid >> 1, wc = wid & 1;
  const int idx = blockIdx.x;
  const int rest = idx >> 3;
  const int cblk = rest % 12;
  const int panel = (rest / 12) * 8 + (idx & 7);
  if (panel >= Mb) return;
  long m0 = (long)panel * 128;
  const int n0 = cblk * 128;
  f32x4 acc[4][4] = {};
  for (int k0 = 0; k0 < 512; k0 += 32) {
    #pragma unroll
    for (int c = tid; c < 512; c += 256) {
      int row = c >> 2, c8 = (c & 3) * 8;
      *(u16x8*)(&As[row * LDT + c8]) = *(const u16x8*)(A + (m0 + row) * 512 + k0 + c8);
      *(u16x8*)(&Bs[row * LDT + c8]) = *(const u16x8*)(B + (long)(n0 + row) * 512 + k0 + c8);
    }
    __syncthreads();
    s16x8 af[4], bfv[4];
    #pragma unroll
    for (int mt = 0; mt < 4; mt++)
      af[mt] = *(const s16x8*)(&As[(wr * 64 + mt * 16 + l15) * LDT + hi * 8]);
    #pragma unroll
    for (int nt = 0; nt < 4; nt++)
      bfv[nt] = *(const s16x8*)(&Bs[(wc * 64 + nt * 16 + l15) * LDT + hi * 8]);
    #pragma unroll
    for (int mt = 0; mt < 4; mt++)
      #pragma unroll
      for (int nt = 0; nt < 4; nt++)
        acc[mt][nt] = __builtin_amdgcn_mfma_f32_16x16x32_bf16(bfv[nt], af[mt], acc[mt][nt], 0, 0, 0);
    __syncthreads();
  }
  #pragma unroll
  for (int mt = 0; mt < 4; mt++) {
    long r = m0 + wr * 64 + mt * 16 + l15;
    if (r < Mstore) {
      #pragma unroll
      for (int nt = 0; nt < 4; nt++) {
        const int col0 = n0 + wc * 64 + nt * 16 + hi * 4;
        u16x4 o;
        #pragma unroll
        for (int i = 0; i < 4; i++) o[i] = f2bf(acc[mt][nt][i]);
        *(u16x4*)(Cout + (long)(col0 >> 6) * zsC + r * 64 + (col0 & 63)) = o;
      }
    }
  }
}

// ===== GEMM: C[M,N] = A(bf16)[M,K] * B(bf16)[N,K]^T (Wo path) =====
template<int BM, int BN, int WM, int WN, int EPI, int GSWAP>
__global__ __launch_bounds__(256) void gemm_bt(
    const unsigned short* __restrict__ A, const unsigned short* __restrict__ B,
    void* __restrict__ Cout, const float* __restrict__ aux,
    int K, int lda, int ldb, int ldc, long zsC, int Mstore)
{
  constexpr int MT = BM / (WM * 16);
  constexpr int NT = BN / (WN * 16);
  constexpr int LDT = 40;
  __shared__ unsigned short As[BM * LDT];
  __shared__ unsigned short Bs[BN * LDT];
  const int tid = threadIdx.x, wid = tid >> 6, lane = tid & 63;
  const int l15 = lane & 15, hi = lane >> 4;
  const int wr = wid / WN, wc = wid % WN;
  const int bx = GSWAP ? blockIdx.y : blockIdx.x;
  const int by = GSWAP ? blockIdx.x : blockIdx.y;
  long m0 = (long)by * BM;
  const int n0 = bx * BN;
  f32x4 acc[MT][NT] = {};
  for (int k0 = 0; k0 < K; k0 += 32) {
    #pragma unroll
    for (int c = tid; c < BM * 4; c += 256) {
      int row = c >> 2, c8 = (c & 3) * 8;
      *(u16x8*)(&As[row * LDT + c8]) = *(const u16x8*)(A + (m0 + row) * lda + k0 + c8);
    }
    #pragma unroll
    for (int c = tid; c < BN * 4; c += 256) {
      int row = c >> 2, c8 = (c & 3) * 8;
      *(u16x8*)(&Bs[row * LDT + c8]) = *(const u16x8*)(B + (long)(n0 + row) * ldb + k0 + c8);
    }
    __syncthreads();
    s16x8 af[MT], bfv[NT];
    #pragma unroll
    for (int mt = 0; mt < MT; mt++)
      af[mt] = *(const s16x8*)(&As[(wr * MT * 16 + mt * 16 + l15) * LDT + hi * 8]);
    #pragma unroll
    for (int nt = 0; nt < NT; nt++)
      bfv[nt] = *(const s16x8*)(&Bs[(wc * NT * 16 + nt * 16 + l15) * LDT + hi * 8]);
    #pragma unroll
    for (int mt = 0; mt < MT; mt++)
      #pragma unroll
      for (int nt = 0; nt < NT; nt++)
        acc[mt][nt] = __builtin_amdgcn_mfma_f32_16x16x32_bf16(bfv[nt], af[mt], acc[mt][nt], 0, 0, 0);
    __syncthreads();
  }
  #pragma unroll
  for (int mt = 0; mt < MT; mt++) {
    long r = m0 + wr * (MT * 16) + mt * 16 + l15;
    if (r < Mstore) {
      #pragma unroll
      for (int nt = 0; nt < NT; nt++) {
        const int col0 = n0 + wc * (NT * 16) + nt * 16 + hi * 4;
        f32x4 v = acc[mt][nt];
        if constexpr (EPI == 8) {
          const f32x4 ax = *(const f32x4*)(aux + r * ldc + col0);
          f32x4 o;
          #pragma unroll
          for (int i = 0; i < 4; i++) o[i] = v[i] + ax[i];
          *(f32x4*)((float*)Cout + r * ldc + col0) = o;
        }
      }
    }
  }
}

// ===== conv GEMM with fused BN2 stats =====
__global__ __launch_bounds__(256) void gemm_conv_bn(
    const unsigned short* __restrict__ A, const unsigned short* __restrict__ B,
    float* __restrict__ out, const float* __restrict__ bias,
    float* __restrict__ s1, float* __restrict__ s2, int Mstore)
{
  constexpr int LDT = 40;
  __shared__ unsigned short As[128 * LDT];
  __shared__ unsigned short Bs[128 * LDT];
  const int tid = threadIdx.x, wid = tid >> 6, lane = tid & 63;
  const int l15 = lane & 15, hi = lane >> 4;
  const int wr = wid >> 1, wc = wid & 1;
  long m0 = (long)blockIdx.y * 128;
  const int n0 = blockIdx.x * 128;
  f32x4 acc[4][4] = {};
  for (int k0 = 0; k0 < 512; k0 += 32) {
    #pragma unroll
    for (int c = tid; c < 512; c += 256) {
      int row = c >> 2, c8 = (c & 3) * 8;
      *(u16x8*)(&As[row * LDT + c8]) = *(const u16x8*)(A + (m0 + row) * 512 + k0 + c8);
      *(u16x8*)(&Bs[row * LDT + c8]) = *(const u16x8*)(B + (long)(n0 + row) * 512 + k0 + c8);
    }
    __syncthreads();
    s16x8 af[4], bfv[4];
    #pragma unroll
    for (int mt = 0; mt < 4; mt++)
      af[mt] = *(const s16x8*)(&As[(wr * 64 + mt * 16 + l15) * LDT + hi * 8]);
    #pragma unroll
    for (int nt = 0; nt < 4; nt++)
      bfv[nt] = *(const s16x8*)(&Bs[(wc * 64 + nt * 16 + l15) * LDT + hi * 8]);
    #pragma unroll
    for (int mt = 0; mt < 4; mt++)
      #pragma unroll
      for (int nt = 0; nt < 4; nt++)
        acc[mt][nt] = __builtin_amdgcn_mfma_f32_16x16x32_bf16(bfv[nt], af[mt], acc[mt][nt], 0, 0, 0);
    __syncthreads();
  }
  float st[4][4] = {};
  float sq[4][4] = {};
  #pragma unroll
  for (int mt = 0; mt < 4; mt++) {
    long r = m0 + wr * 64 + mt * 16 + l15;
    bool valid = r < Mstore;
    #pragma unroll
    for (int nt = 0; nt < 4; nt++) {
      const int col0 = n0 + wc * 64 + nt * 16 + hi * 4;
      f32x4 o = {0.f, 0.f, 0.f, 0.f};
      if (valid) {
        float* cp = out + r * 512 + col0;
        f32x4 cur = *(f32x4*)cp;
        #pragma unroll
        for (int i = 0; i < 4; i++) {
          float cv = acc[mt][nt][i] + bias[col0 + i];
          cv = cv > 0.f ? cv : 0.f;
          o[i] = cur[i] + cv;
        }
        *(f32x4*)cp = o;
      }
      #pragma unroll
      for (int i = 0; i < 4; i++) { st[nt][i] += o[i]; sq[nt][i] += o[i] * o[i]; }
    }
  }
  #pragma unroll
  for (int nt = 0; nt < 4; nt++)
    #pragma unroll
    for (int i = 0; i < 4; i++) {
      float a = st[nt][i], b = sq[nt][i];
      a += __shfl_xor(a, 1); a += __shfl_xor(a, 2); a += __shfl_xor(a, 4); a += __shfl_xor(a, 8);
      b += __shfl_xor(b, 1); b += __shfl_xor(b, 2); b += __shfl_xor(b, 4); b += __shfl_xor(b, 8);
      if (l15 == 0) {
        const int col = n0 + wc * 64 + nt * 16 + hi * 4 + i;
        atomicAdd(&s1[col], a);
        atomicAdd(&s2[col], b);
      }
    }
}

// ===== k-side pass 1: per-graph-per-head max of u (no stores); 1D grid, bh=idx&255 =====
__global__ __launch_bounds__(256, 4) void k_kmax(
    const unsigned short* __restrict__ kvqh, const unsigned short* __restrict__ projb,
    const unsigned int* __restrict__ offs, unsigned int* __restrict__ kmax, long Npad) {
  __shared__ float wmax[4];
  const int tid = threadIdx.x, wid = tid >> 6, lane = tid & 63;
  const int bh = blockIdx.x & 255, xb = blockIdx.x >> 8;
  const int b = bh >> 3, h = bh & 7;
  const unsigned int off = offs[b];
  const int nb = (int)(offs[b + 1] - off);
  const int m0 = xb * 64;
  if (m0 >= nb) return;
  const unsigned short* A = kvqh + ((long)(8 + h) * Npad + off + m0) * 64;
  f32x4 acc[4][4] = {};
  #pragma unroll
  for (int k0 = 0; k0 < 64; k0 += 32) {
    s16x8 af[4], bfv[4];
    #pragma unroll
    for (int mt = 0; mt < 4; mt++)
      af[mt] = *(const s16x8*)(A + (long)(mt * 16 + (lane & 15)) * 64 + k0 + ((lane >> 4) * 8));
    #pragma unroll
    for (int nt = 0; nt < 4; nt++)
      bfv[nt] = *(const s16x8*)(projb + (long)(wid * 64 + nt * 16 + (lane & 15)) * 64 + k0 + ((lane >> 4) * 8));
    __builtin_amdgcn_s_setprio(1);
    #pragma unroll
    for (int mt = 0; mt < 4; mt++)
      #pragma unroll
      for (int nt = 0; nt < 4; nt++)
        acc[mt][nt] = __builtin_amdgcn_mfma_f32_16x16x32_bf16(af[mt], bfv[nt], acc[mt][nt], 0, 0, 0);
    __builtin_amdgcn_s_setprio(0);
  }
  float bm = -3.0e38f;
  #pragma unroll
  for (int mt = 0; mt < 4; mt++)
    #pragma unroll
    for (int i = 0; i < 4; i++) {
      int row = mt * 16 + ((lane >> 4) << 2) + i;
      if (m0 + row < nb) {
        #pragma unroll
        for (int nt = 0; nt < 4; nt++) bm = fmaxf(bm, acc[mt][nt][i]);
      }
    }
  #pragma unroll
  for (int s = 1; s < 64; s <<= 1) bm = fmaxf(bm, __shfl_xor(bm, s));
  if (lane == 0) wmax[wid] = bm;
  __syncthreads();
  if (tid == 0) {
    float m = fmaxf(fmaxf(wmax[0], wmax[1]), fmaxf(wmax[2], wmax[3]));
    atomicMax(&kmax[b * 8 + h], __float_as_uint(fmaxf(m, 0.f)));
  }
}

// ===== k-side pass 2: m-split kv accumulation; kfsum -> bf16 row 64; 1D grid =====
__global__ __launch_bounds__(256) void k_kvm(
    const unsigned short* __restrict__ kvqh, const unsigned short* __restrict__ projb,
    const unsigned int* __restrict__ offs, const unsigned int* __restrict__ kmax,
    unsigned short* __restrict__ kvTb, long Npad) {
  constexpr int TLD = 72;
  __shared__ unsigned short vsT[2][64 * TLD];
  __shared__ unsigned short kfsT[64 * TLD];
  const int tid = threadIdx.x, wid = tid >> 6, lane = tid & 63;
  const int bh = blockIdx.x & 255, mblk = blockIdx.x >> 8;
  const int b = bh >> 3, h = bh & 7;
  const unsigned int off = offs[b];
  const int nb = (int)(offs[b + 1] - off);
  const float km = __uint_as_float(kmax[b * 8 + h]);
  const unsigned short* Kp = kvqh + ((long)(8 + h) * Npad + off) * 64;
  const unsigned short* Vp = kvqh + ((long)(16 + h) * Npad + off) * 64;
  const unsigned short* Pp = projb + (long)(mblk * 64 + wid * 16) * 64;
  const int l15 = lane & 15, hi = lane >> 4;
  const int mloc = wid * 16 + l15;

  #pragma unroll
  for (int c = tid; c < 512; c += 256) {
    int row = c >> 3, c8 = (c & 7) * 8;
    int rot = (c & 7) * 8;
    u16x8 v = *(const u16x8*)(Vp + (long)row * 64 + c8);
    #pragma unroll
    for (int j = 0; j < 8; j++) vsT[0][(c8 + j) * TLD + ((row + rot) & 63)] = v[j];
  }
  __syncthreads();

  f32x4 akv[4] = {};
  float ksum = 0.f;
  int buf = 0;
  for (int n0 = 0; n0 < nb; n0 += 64) {
    f32x4 acc[4] = {};
    float dsum[4] = {0.f, 0.f, 0.f, 0.f};
    #pragma unroll
    for (int k0 = 0; k0 < 64; k0 += 32) {
      s16x8 af[4];
      #pragma unroll
      for (int mt = 0; mt < 4; mt++)
        af[mt] = *(const s16x8*)(Kp + ((long)n0 + mt * 16 + l15) * 64 + k0 + hi * 8);
      s16x8 bfv = *(const s16x8*)(Pp + (long)l15 * 64 + k0 + hi * 8);
      __builtin_amdgcn_s_setprio(1);
      #pragma unroll
      for (int mt = 0; mt < 4; mt++) {
        #pragma unroll
        for (int j = 0; j < 8; j++) {
          float a = bf2f((unsigned short)af[mt][j]);
          dsum[mt] += a * a;
        }
        acc[mt] = __builtin_amdgcn_mfma_f32_16x16x32_bf16(af[mt], bfv, acc[mt], 0, 0, 0);
      }
      __builtin_amdgcn_s_setprio(0);
    }
    float rs[4];
    #pragma unroll
    for (int mt = 0; mt < 4; mt++) {
      float s = dsum[mt];
      s += __shfl_xor(s, 16); s += __shfl_xor(s, 32);
      rs[mt] = 0.0625f * s;
    }
    #pragma unroll
    for (int mt = 0; mt < 4; mt++) {
      int r0 = mt * 16 + hi * 4;
      float e[4];
      #pragma unroll
      for (int i = 0; i < 4; i++) {
        float dg = __shfl(rs[mt], hi * 4 + i);
        e[i] = (n0 + r0 + i < nb) ? (__expf(acc[mt][i] - dg - km) * 0.0625f + 1e-6f) : 0.f;
      }
      ksum += e[0] + e[1] + e[2] + e[3];
      unsigned int p0 = (unsigned int)f2bf(e[0]) | ((unsigned int)f2bf(e[1]) << 16);
      unsigned int p1 = (unsigned int)f2bf(e[2]) | ((unsigned int)f2bf(e[3]) << 16);
      *(unsigned int*)(&kfsT[mloc * TLD + r0]) = p0;
      *(unsigned int*)(&kfsT[mloc * TLD + r0 + 2]) = p1;
    }
    if (n0 + 64 < nb) {
      #pragma unroll
      for (int c = tid; c < 512; c += 256) {
        int row = c >> 3, c8 = (c & 7) * 8;
        int rot = (c & 7) * 8;
        u16x8 v = *(const u16x8*)(Vp + ((long)n0 + 64 + row) * 64 + c8);
        #pragma unroll
        for (int j = 0; j < 8; j++) vsT[buf ^ 1][(c8 + j) * TLD + ((row + rot) & 63)] = v[j];
      }
    }
    __builtin_amdgcn_s_setprio(1);
    #pragma unroll
    for (int ks = 0; ks < 2; ks++) {
      s16x8 bB = *(const s16x8*)(&kfsT[mloc * TLD + ks * 32 + hi * 8]);
      #pragma unroll
      for (int mt2 = 0; mt2 < 4; mt2++) {
        int d = mt2 * 16 + l15;
        int rrot = ((ks * 32 + hi * 8) + ((d >> 3) & 7) * 8) & 63;
        s16x8 aA = *(const s16x8*)(&vsT[buf][d * TLD + rrot]);
        akv[mt2] = __builtin_amdgcn_mfma_f32_16x16x32_bf16(aA, bB, akv[mt2], 0, 0, 0);
      }
    }
    __builtin_amdgcn_s_setprio(0);
    __syncthreads();
    buf ^= 1;
  }
  long base = ((long)b * 8 + h) * (KVROWS * 256);
  const int m = mblk * 64 + mloc;
  #pragma unroll
  for (int mt2 = 0; mt2 < 4; mt2++)
    #pragma unroll
    for (int i = 0; i < 4; i++) {
      int d = mt2 * 16 + hi * 4 + i;
      kvTb[base + (long)d * 256 + m] = f2bf(akv[mt2][i]);
    }
  ksum += __shfl_xor(ksum, 16); ksum += __shfl_xor(ksum, 32);
  if (hi == 0) kvTb[base + 64 * 256 + m] = f2bf(ksum);
}

// ===== query-side flash (session best: 64-row tile, bounds(256,4)): swapped layout,
// packed stores, fused denominator, PV prefetch + setprio; 1D XCD-local grid =====
__global__ __launch_bounds__(256, 4) void k_qflash(
    const unsigned short* __restrict__ qh_all, const unsigned short* __restrict__ projb,
    const unsigned short* __restrict__ kvTb, const unsigned int* __restrict__ offs,
    unsigned short* __restrict__ attn, long Npad) {
  constexpr int QLDT = 264;
  __shared__ unsigned short qfs[64 * QLDT];
  __shared__ float smax[4][64];
  const int tid = threadIdx.x, wid = tid >> 6, lane = tid & 63;
  const int l15 = lane & 15, hi = lane >> 4;
  const int bh = blockIdx.x & 255, xb = blockIdx.x >> 8;
  const int b = bh >> 3, h = bh & 7;
  const unsigned int off = offs[b];
  const int nb = (int)(offs[b + 1] - off);
  const int m0 = xb * 64;
  if (m0 >= nb) return;
  const unsigned short* A = qh_all + ((long)h * Npad + off + m0) * 64;

  f32x4 acc[4][4] = {};
  float dsum[4] = {0.f, 0.f, 0.f, 0.f};
  #pragma unroll
  for (int k0 = 0; k0 < 64; k0 += 32) {
    s16x8 af[4], bfv[4];
    #pragma unroll
    for (int mt = 0; mt < 4; mt++)
      af[mt] = *(const s16x8*)(A + (long)(mt * 16 + l15) * 64 + k0 + hi * 8);
    #pragma unroll
    for (int nt = 0; nt < 4; nt++)
      bfv[nt] = *(const s16x8*)(projb + (long)(wid * 64 + nt * 16 + l15) * 64 + k0 + hi * 8);
    #pragma unroll
    for (int mt = 0; mt < 4; mt++)
      #pragma unroll
      for (int j = 0; j < 8; j++) {
        float a = bf2f((unsigned short)af[mt][j]);
        dsum[mt] += a * a;
      }
    __builtin_amdgcn_s_setprio(1);
    #pragma unroll
    for (int mt = 0; mt < 4; mt++)
      #pragma unroll
      for (int nt = 0; nt < 4; nt++)
        acc[mt][nt] = __builtin_amdgcn_mfma_f32_16x16x32_bf16(bfv[nt], af[mt], acc[mt][nt], 0, 0, 0);
    __builtin_amdgcn_s_setprio(0);
  }
  float diag[4];
  #pragma unroll
  for (int mt = 0; mt < 4; mt++) {
    float s = dsum[mt];
    s += __shfl_xor(s, 16); s += __shfl_xor(s, 32);
    diag[mt] = 0.0625f * s;
  }
  #pragma unroll
  for (int mt = 0; mt < 4; mt++) {
    float m = acc[mt][0][0];
    #pragma unroll
    for (int nt = 0; nt < 4; nt++)
      #pragma unroll
      for (int i = 0; i < 4; i++) m = fmaxf(m, acc[mt][nt][i]);
    m = fmaxf(m, __shfl_xor(m, 16)); m = fmaxf(m, __shfl_xor(m, 32));
    if (hi == 0) smax[wid][mt * 16 + l15] = m;
  }
  __syncthreads();
  #pragma unroll
  for (int mt = 0; mt < 4; mt++) {
    int row = mt * 16 + l15;
    float rm = fmaxf(fmaxf(smax[0][row], smax[1][row]), fmaxf(smax[2][row], smax[3][row]));
    float sub = diag[mt] + rm;
    #pragma unroll
    for (int nt = 0; nt < 4; nt++) {
      u16x4 o;
      #pragma unroll
      for (int i = 0; i < 4; i++)
        o[i] = f2bf(__expf(acc[mt][nt][i] - sub) * 0.0625f + 1e-6f);
      *(u16x4*)(&qfs[row * QLDT + wid * 64 + nt * 16 + hi * 4]) = o;
    }
  }
  __syncthreads();
  const unsigned short* kvb = kvTb + ((long)b * 8 + h) * (KVROWS * 256);
  f32x4 acc2[4] = {};
  f32x4 acc3 = {};
  s16x8 bkc[5];
  #pragma unroll
  for (int t = 0; t < 5; t++)
    bkc[t] = *(const s16x8*)(kvb + (long)(t * 16 + l15) * 256 + hi * 8);
  #pragma unroll
  for (int ks = 0; ks < 8; ks++) {
    s16x8 bkn[5];
    if (ks < 7) {
      #pragma unroll
      for (int t = 0; t < 5; t++)
        bkn[t] = *(const s16x8*)(kvb + (long)(t * 16 + l15) * 256 + (ks + 1) * 32 + hi * 8);
    }
    s16x8 aq = *(const s16x8*)(&qfs[(wid * 16 + l15) * QLDT + ks * 32 + hi * 8]);
    __builtin_amdgcn_s_setprio(1);
    #pragma unroll
    for (int t = 0; t < 4; t++)
      acc2[t] = __builtin_amdgcn_mfma_f32_16x16x32_bf16(bkc[t], aq, acc2[t], 0, 0, 0);
    acc3 = __builtin_amdgcn_mfma_f32_16x16x32_bf16(bkc[4], aq, acc3, 0, 0, 0);
    __builtin_amdgcn_s_setprio(0);
    if (ks < 7) {
      #pragma unroll
      for (int t = 0; t < 5; t++) bkc[t] = bkn[t];
    }
  }
  float zden = __shfl(acc3[0], l15);
  float zr = 1.f / (zden + 1e-6f);
  int row = wid * 16 + l15;
  if (m0 + row < nb) {
    unsigned short* po = attn + (long)(off + m0 + row) * 512 + h * 64;
    #pragma unroll
    for (int t = 0; t < 4; t++) {
      u16x4 o;
      #pragma unroll
      for (int i = 0; i < 4; i++) o[i] = f2bf(acc2[t][i] * zr);
      *(u16x4*)(po + t * 16 + hi * 4) = o;
    }
  }
}

// ===== small kernels =====

__global__ void k_fill(float* __restrict__ out, long n, float v) {
  long i = (long)blockIdx.x * 256 + threadIdx.x;
  if (i < n) out[i] = v;
}

__global__ void k_convx_stats(const float* __restrict__ x, unsigned short* __restrict__ xb,
                              float* __restrict__ s1, float* __restrict__ s2, int N, int rpb) {
  int t = threadIdx.x;
  int r0 = blockIdx.x * rpb;
  int r1 = min(N, r0 + rpb);
  float a1 = 0, a2 = 0, b1 = 0, b2 = 0;
  for (int r = r0; r < r1; r++) {
    const float* xr = x + (long)r * 512 + 2 * t;
    float va = xr[0], vb = xr[1];
    a1 += va; a2 += va * va; b1 += vb; b2 += vb * vb;
    *(unsigned int*)(xb + (long)r * 512 + 2 * t) =
        (unsigned int)f2bf(va) | ((unsigned int)f2bf(vb) << 16);
  }
  atomicAdd(&s1[2 * t], a1); atomicAdd(&s2[2 * t], a2);
  atomicAdd(&s1[2 * t + 1], b1); atomicAdd(&s2[2 * t + 1], b2);
}

__global__ void k_transall(const float* __restrict__ w0, const float* __restrict__ w1,
                           const float* __restrict__ w2, const float* __restrict__ w3,
                           const float* __restrict__ w4, unsigned short* __restrict__ out) {
  long idx = (long)blockIdx.x * 256 + threadIdx.x;
  if (idx >= (5L << 18)) return;
  int which = (int)(idx >> 18);
  int r = (int)(idx & 262143);
  int n = r >> 9, k = r & 511;
  const float* w = which == 0 ? w0 : which == 1 ? w1 : which == 2 ? w2 : which == 3 ? w3 : w4;
  out[idx] = f2bf(w[k * 512 + n]);
}

__global__ void k_scale_copy_bf(const float* __restrict__ in, unsigned short* __restrict__ out,
                                int n, float scl) {
  int i = blockIdx.x * 256 + threadIdx.x;
  if (i < n) out[i] = f2bf(in[i] * scl);
}

__global__ void k_bn_final(const float* __restrict__ s1, const float* __restrict__ s2,
                           const float* __restrict__ g, const float* __restrict__ b,
                           float* __restrict__ a, float* __restrict__ c, float invN) {
  int t = threadIdx.x;
  float mu = s1[t] * invN;
  float var = s2[t] * invN - mu * mu;
  float inv = rsqrtf(var + 1e-5f);
  float av = g[t] * inv;
  a[t] = av;
  c[t] = b[t] - mu * av;
}

__global__ void k_deg(const int* __restrict__ ed, unsigned int* __restrict__ deg, long E) {
  long i = (long)blockIdx.x * 256 + threadIdx.x;
  if (i < E) atomicAdd(&deg[ed[i]], 1u);
}

__global__ void k_offs(const int* __restrict__ batch, unsigned int* __restrict__ offs, int N) {
  int i = blockIdx.x * 256 + threadIdx.x;
  if (i >= N) return;
  int b = batch[i];
  if (i == 0) { for (int bb = 0; bb <= b; bb++) offs[bb] = 0; }
  else {
    int pb = batch[i - 1];
    if (pb != b) for (int bb = pb + 1; bb <= b; bb++) offs[bb] = i;
  }
  if (i == N - 1) { for (int bb = b + 1; bb <= 32; bb++) offs[bb] = N; }
}

__global__ __launch_bounds__(1024) void k_scan_nodes(const unsigned int* __restrict__ deg,
                                                     unsigned int* __restrict__ rowstart, int N) {
  __shared__ unsigned int wsum[16];
  __shared__ unsigned int carry_s;
  int t = threadIdx.x, lane = t & 63, wid = t >> 6;
  if (t == 0) carry_s = 0;
  __syncthreads();
  for (int base = 0; base < N; base += 1024) {
    int i = base + t;
    unsigned int v = (i < N) ? deg[i] : 0;
    unsigned int sc = v;
    #pragma unroll
    for (int s = 1; s < 64; s <<= 1) {
      unsigned int u = __shfl_up(sc, s);
      if (lane >= s) sc += u;
    }
    if (lane == 63) wsum[wid] = sc;
    __syncthreads();
    unsigned int woff = 0, tot = 0;
    #pragma unroll
    for (int w = 0; w < 16; w++) { unsigned int s = wsum[w]; if (w < wid) woff += s; tot += s; }
    unsigned int carry = carry_s;
    if (i < N) rowstart[i] = carry + woff + sc - v;
    __syncthreads();
    if (t == 0) carry_s = carry + tot;
    __syncthreads();
  }
  if (threadIdx.x == 0) rowstart[N] = carry_s;
}

__global__ void k_csr_fill(const int* __restrict__ es, const int* __restrict__ ed,
                           const unsigned int* __restrict__ rowstart,
                           unsigned int* __restrict__ cursor, int* __restrict__ csr, long E) {
  long e = (long)blockIdx.x * 256 + threadIdx.x;
  if (e >= E) return;
  int d = ed[e];
  unsigned int slot = atomicAdd(&cursor[d], 1u);
  csr[rowstart[d] + slot] = es[e];
}

// gather from bf16 xbf; fused deg-normalize + BN1 affine
__global__ __launch_bounds__(128) void k_gather(const int* __restrict__ csr,
                                                const unsigned int* __restrict__ rowstart,
                                                const unsigned short* __restrict__ xb,
                                                const float* __restrict__ a1, const float* __restrict__ c1,
                                                unsigned short* __restrict__ conv_in, int N) {
  long n = blockIdx.x;
  int c = threadIdx.x * 4;
  u16x4 o; o[0] = 0; o[1] = 0; o[2] = 0; o[3] = 0;
  if (n < N) {
    unsigned int r0 = rowstart[n], r1 = rowstart[n + 1];
    if (r1 > r0) {
      f32x4 acc0 = {}, acc1 = {};
      unsigned int j = r0;
      for (; j + 2 <= r1; j += 2) {
        u16x4 v0 = *(const u16x4*)(xb + (long)csr[j] * 512 + c);
        u16x4 v1 = *(const u16x4*)(xb + (long)csr[j + 1] * 512 + c);
        #pragma unroll
        for (int i = 0; i < 4; i++) { acc0[i] += bf2f(v0[i]); acc1[i] += bf2f(v1[i]); }
      }
      if (j < r1) {
        u16x4 v0 = *(const u16x4*)(xb + (long)csr[j] * 512 + c);
        #pragma unroll
        for (int i = 0; i < 4; i++) acc0[i] += bf2f(v0[i]);
      }
      f32x4 acc = acc0 + acc1;
      float inv = 1.f / (float)(r1 - r0);
      o[0] = f2bf(acc[0] * inv * a1[c + 0] + c1[c + 0]);
      o[1] = f2bf(acc[1] * inv * a1[c + 1] + c1[c + 1]);
      o[2] = f2bf(acc[2] * inv * a1[c + 2] + c1[c + 2]);
      o[3] = f2bf(acc[3] * inv * a1[c + 3] + c1[c + 3]);
    }
  }
  *(u16x4*)(conv_in + n * 512 + c) = o;
}

__global__ void k_bn_apply(float* __restrict__ y, const float* __restrict__ a,
                           const float* __restrict__ c, long total) {
  long i4 = ((long)blockIdx.x * 256 + threadIdx.x) * 4;
  if (i4 >= total) return;
  int col = (int)(i4 & 511);
  f32x4 v = *(const f32x4*)(y + i4);
  #pragma unroll
  for (int j = 0; j < 4; j++) v[j] = v[j] * a[col + j] + c[col + j];
  *(f32x4*)(y + i4) = v;
}

// ===== host =====

extern "C" void kernel_launch(void* const* d_in, const int* in_sizes, int n_in,
                              void* d_out, int out_size, void* d_ws, size_t ws_size,
                              hipStream_t stream) {
  (void)n_in; (void)out_size;
  const float* x = (const float*)d_in[0];
  const int* batch = (const int*)d_in[1];
  const int* eidx = (const int*)d_in[2];
  const float* n1g = (const float*)d_in[3];
  const float* n1b = (const float*)d_in[4];
  const float* n2g = (const float*)d_in[5];
  const float* n2b = (const float*)d_in[6];
  const float* wconv = (const float*)d_in[7];
  const float* bconv = (const float*)d_in[8];
  const float* wq = (const float*)d_in[9];
  const float* wk = (const float*)d_in[10];
  const float* wv = (const float*)d_in[11];
  const float* wo = (const float*)d_in[12];
  const float* proj = (const float*)d_in[13];

  const int N = in_sizes[1];
  const long E = in_sizes[2] / 2;
  const long Npad = CDIV(N, 128) * 128 + 256;
  const int Mb = (int)((CDIV(N, 128) * 128 + 128) / 128);  // QKV panel count (padded)
  const int MbC = CDIV(N, 128);                            // exact panel count for out-path GEMMs
  const int* es = eidx;
  const int* ed = eidx + E;
  float* out = (float*)d_out;

  char* p = (char*)d_ws;
  auto alloc = [&](size_t bytes) -> char* {
    char* r = p;
    p += (bytes + 255) & ~(size_t)255;
    return r;
  };
  unsigned short* kvqh = (unsigned short*)alloc((size_t)24 * Npad * 64 * 2);  // q:0-7,k:8-15,v:16-23 (k+v -> attn)
  unsigned short* xbf  = (unsigned short*)alloc((size_t)Npad * 512 * 2);      // x bf16 (gather source)
  unsigned short* conv_in = (unsigned short*)alloc((size_t)Npad * 512 * 2);   // gather output
  unsigned short* kvT_b = (unsigned short*)alloc((size_t)32 * 8 * KVROWS * 256 * 2);
  unsigned short* wts   = (unsigned short*)alloc((size_t)5 * 512 * 512 * 2);  // q|k|v|conv|o transposed
  unsigned short* proj_s = (unsigned short*)alloc((size_t)256 * 64 * 2);
  float* bn1_acc = (float*)alloc(1024 * 4);
  float* bn1_ac  = (float*)alloc(1024 * 4);
  float* bn2_acc = (float*)alloc(1024 * 4);
  float* bn2_ac  = (float*)alloc(1024 * 4);
  unsigned int* deg      = (unsigned int*)alloc((size_t)N * 4);
  unsigned int* offs     = (unsigned int*)alloc(33 * 4);
  unsigned int* kmax     = (unsigned int*)alloc(32 * 8 * 4);
  unsigned int* rowstart = (unsigned int*)alloc((size_t)(N + 1) * 4);
  unsigned int* cursor   = (unsigned int*)alloc((size_t)N * 4);
  int* csr               = (int*)alloc((size_t)E * 4);
  size_t required = (size_t)(p - (char*)d_ws);
  if (required > ws_size) {
    k_fill<<<(int)CDIV((long)N * 512, 256), 256, 0, stream>>>(
        out, (long)N * 512, 1.0e6f + (float)(ws_size >> 20));
    return;
  }
  unsigned short* wqkv_t  = wts;
  unsigned short* wconv_t = wts + 3 * 512 * 512;
  unsigned short* wo_t    = wts + 4 * 512 * 512;
  unsigned short* attn2   = kvqh + (size_t)8 * Npad * 64;  // overlays k+v heads (dead after kvm)

  // ---- zero accumulators (ws is not re-poisoned between replays) ----
  hipMemsetAsync(deg, 0, (size_t)N * 4, stream);
  hipMemsetAsync(cursor, 0, (size_t)N * 4, stream);
  hipMemsetAsync(kmax, 0, 32 * 8 * 4, stream);
  hipMemsetAsync(bn1_acc, 0, 1024 * 4, stream);
  hipMemsetAsync(bn2_acc, 0, 1024 * 4, stream);
  hipMemsetAsync(xbf + (size_t)N * 512, 0, (size_t)(Npad - N) * 512 * 2, stream);

  // ---- prep ----
  int rpb = CDIV(N, 1024);
  k_convx_stats<<<1024, 256, 0, stream>>>(x, xbf, bn1_acc, bn1_acc + 512, N, rpb);
  k_transall<<<(int)CDIV(5L << 18, 256), 256, 0, stream>>>(wq, wk, wv, wconv, wo, wts);
  k_scale_copy_bf<<<CDIV(256 * 64, 256), 256, 0, stream>>>(proj, proj_s, 256 * 64, 0.35355339059327373f);
  k_bn_final<<<1, 512, 0, stream>>>(bn1_acc, bn1_acc + 512, n1g, n1b, bn1_ac, bn1_ac + 512, 1.f / N);
  k_deg<<<(int)CDIV(E, 256), 256, 0, stream>>>(ed, deg, E);
  k_offs<<<CDIV(N, 256), 256, 0, stream>>>(batch, offs, N);
  k_scan_nodes<<<1, 1024, 0, stream>>>(deg, rowstart, N);
  k_csr_fill<<<(int)CDIV(E, 256), 256, 0, stream>>>(es, ed, rowstart, cursor, csr, E);

  // ---- QKV: 1D XCD-local grid (panel's 12 col-blocks on same XCD, back-to-back) ----
  const int MbP8 = CDIV(Mb, 8) * 8;
  gemm_qkv<<<MbP8 * 12, 256, 0, stream>>>(
      xbf, wqkv_t, kvqh, Mb, (long)Npad * 64, (int)Npad);

  // ---- keys: max pass, then m-split kv accumulation (1D XCD-local grids) ----
  k_kmax<<<32 * 256, 256, 0, stream>>>(kvqh, proj_s, offs, kmax, Npad);
  k_kvm<<<4 * 256, 256, 0, stream>>>(kvqh, proj_s, offs, kmax, kvT_b, Npad);

  // ---- GNN conv gather (reads bf16 xbf, writes dedicated conv_in) ----
  k_gather<<<MbC * 128, 128, 0, stream>>>(csr, rowstart, xbf, bn1_ac, bn1_ac + 512, conv_in, N);

  // ---- queries: 64-row flash kernel (session best); attn into dead k/v region ----
  k_qflash<<<32 * 256, 256, 0, stream>>>(
      kvqh, proj_s, kvT_b, offs, attn2, Npad);

  // ---- output projection + residual x (EPI8, col-fast grid order) ----
  gemm_bt<128, 128, 2, 2, 8, 0><<<dim3(4, MbC), 256, 0, stream>>>(
      attn2, wo_t, out, x, 512, 512, 512, 512, 0, N);

  // ---- conv GEMM + fused BN2 stats (last writer of out; col-fast grid order) ----
  gemm_conv_bn<<<dim3(4, MbC), 256, 0, stream>>>(
      conv_in, wconv_t, out, bconv, bn2_acc, bn2_acc + 512, N);

  // ---- BN2 finalize + apply ----
  k_bn_final<<<1, 512, 0, stream>>>(bn2_acc, bn2_acc + 512, n2g, n2b, bn2_ac, bn2_ac + 512, 1.f / N);
  k_bn_apply<<<(int)CDIV((long)N * 512 / 4, 256), 256, 0, stream>>>(out, bn2_ac, bn2_ac + 512, (long)N * 512);
}